// Round 1
// baseline (507.584 us; speedup 1.0000x reference)
//
#include <hip/hip_runtime.h>

#define N_FEAT 64
#define EPG 80   // edges per 16-lane group; avg segment len = 12.5 -> ~6.4 segs/chunk

__global__ __launch_bounds__(256) void cfconv_kernel(
    const float* __restrict__ x, const float* __restrict__ Wij,
    const int* __restrict__ idx_i, const int* __restrict__ idx_j,
    float* __restrict__ y, int n_edges)
{
    const int gid  = (blockIdx.x * blockDim.x + threadIdx.x) >> 4;  // 16-lane group id
    const int lane = threadIdx.x & 15;
    const long e0 = (long)gid * EPG;
    if (e0 >= n_edges) return;
    const long e1 = (e0 + EPG < n_edges) ? (e0 + EPG) : (long)n_edges;
    const int f = lane * 4;

    float4 acc = make_float4(0.f, 0.f, 0.f, 0.f);
    int cur = idx_i[e0];

    for (long e = e0; e < e1; ++e) {
        const int i = idx_i[e];   // uniform within group (broadcast load)
        const int j = idx_j[e];
        if (i != cur) {
            float* yp = y + (size_t)cur * N_FEAT + f;
            atomicAdd(yp + 0, acc.x);
            atomicAdd(yp + 1, acc.y);
            atomicAdd(yp + 2, acc.z);
            atomicAdd(yp + 3, acc.w);
            acc = make_float4(0.f, 0.f, 0.f, 0.f);
            cur = i;
        }
        const float4 w  = *reinterpret_cast<const float4*>(Wij + (size_t)e * N_FEAT + f);
        const float4 xv = *reinterpret_cast<const float4*>(x   + (size_t)j * N_FEAT + f);
        acc.x += w.x * xv.x;
        acc.y += w.y * xv.y;
        acc.z += w.z * xv.z;
        acc.w += w.w * xv.w;
    }
    float* yp = y + (size_t)cur * N_FEAT + f;
    atomicAdd(yp + 0, acc.x);
    atomicAdd(yp + 1, acc.y);
    atomicAdd(yp + 2, acc.z);
    atomicAdd(yp + 3, acc.w);
}

extern "C" void kernel_launch(void* const* d_in, const int* in_sizes, int n_in,
                              void* d_out, int out_size, void* d_ws, size_t ws_size,
                              hipStream_t stream) {
    const float* x     = (const float*)d_in[0];
    const float* Wij   = (const float*)d_in[1];
    const int*   idx_i = (const int*)d_in[2];
    const int*   idx_j = (const int*)d_in[3];
    float*       y     = (float*)d_out;
    const int n_edges  = in_sizes[2];

    // d_out is poisoned to 0xAA before every timed launch; atoms with no
    // edges must read 0 -> zero it first (stream memset is graph-capturable).
    hipMemsetAsync(d_out, 0, (size_t)out_size * sizeof(float), stream);

    const int groups = (n_edges + EPG - 1) / EPG;
    const int blocks = (groups * 16 + 255) / 256;   // 16 groups per 256-thread block
    cfconv_kernel<<<blocks, 256, 0, stream>>>(x, Wij, idx_i, idx_j, y, n_edges);
}

// Round 2
// 464.818 us; speedup vs baseline: 1.0920x; 1.0920x over previous
//
#include <hip/hip_runtime.h>

#define NF 64

// Pass 1: CSR row offsets from sorted idx_i.
// offsets[a] = lower_bound(idx_i, a); offsets[n_atoms] = n_edges.
// Each edge thread fills the (gap) range it is the boundary of; ranges are
// disjoint, every entry in [0, n_atoms] is written exactly once.
__global__ __launch_bounds__(256) void build_offsets(
    const int* __restrict__ idx_i, int* __restrict__ offsets,
    int n_edges, int n_atoms)
{
    const int e = blockIdx.x * blockDim.x + threadIdx.x;
    if (e >= n_edges) return;
    const int cur  = idx_i[e];
    const int prev = (e == 0) ? -1 : idx_i[e - 1];
    for (int a = prev + 1; a <= cur; ++a) offsets[a] = e;
    if (e == n_edges - 1)
        for (int a = cur + 1; a <= n_atoms; ++a) offsets[a] = n_edges;
}

// Pass 2: one 16-lane group per atom. Lane owns a float4 feature slice
// (16 x 16B = full 256B row, coalesced). Edges of an atom are contiguous
// (idx_i sorted) -> Wij/idx_j reads stay streaming. No atomics; plain store
// writes every row (zeros for atoms with no edges), so no d_out memset needed.
__global__ __launch_bounds__(256) void cfconv_gather(
    const float* __restrict__ x, const float* __restrict__ Wij,
    const int* __restrict__ idx_j, const int* __restrict__ offsets,
    float* __restrict__ y, int n_atoms)
{
    const int g    = (blockIdx.x * blockDim.x + threadIdx.x) >> 4;
    const int lane = threadIdx.x & 15;
    if (g >= n_atoms) return;
    const int s = offsets[g];
    const int t = offsets[g + 1];
    const int f = lane * 4;

    float4 a0 = make_float4(0.f, 0.f, 0.f, 0.f);
    float4 a1 = make_float4(0.f, 0.f, 0.f, 0.f);

    int e = s;
    for (; e + 2 <= t; e += 2) {
        const int j0 = idx_j[e];
        const int j1 = idx_j[e + 1];
        const float4 w0 = *reinterpret_cast<const float4*>(Wij + (size_t)e       * NF + f);
        const float4 w1 = *reinterpret_cast<const float4*>(Wij + (size_t)(e + 1) * NF + f);
        const float4 x0 = *reinterpret_cast<const float4*>(x   + (size_t)j0      * NF + f);
        const float4 x1 = *reinterpret_cast<const float4*>(x   + (size_t)j1      * NF + f);
        a0.x += w0.x * x0.x; a0.y += w0.y * x0.y; a0.z += w0.z * x0.z; a0.w += w0.w * x0.w;
        a1.x += w1.x * x1.x; a1.y += w1.y * x1.y; a1.z += w1.z * x1.z; a1.w += w1.w * x1.w;
    }
    if (e < t) {
        const int j0 = idx_j[e];
        const float4 w0 = *reinterpret_cast<const float4*>(Wij + (size_t)e  * NF + f);
        const float4 x0 = *reinterpret_cast<const float4*>(x   + (size_t)j0 * NF + f);
        a0.x += w0.x * x0.x; a0.y += w0.y * x0.y; a0.z += w0.z * x0.z; a0.w += w0.w * x0.w;
    }

    a0.x += a1.x; a0.y += a1.y; a0.z += a1.z; a0.w += a1.w;
    *reinterpret_cast<float4*>(y + (size_t)g * NF + f) = a0;
}

extern "C" void kernel_launch(void* const* d_in, const int* in_sizes, int n_in,
                              void* d_out, int out_size, void* d_ws, size_t ws_size,
                              hipStream_t stream) {
    const float* x     = (const float*)d_in[0];
    const float* Wij   = (const float*)d_in[1];
    const int*   idx_i = (const int*)d_in[2];
    const int*   idx_j = (const int*)d_in[3];
    float*       y     = (float*)d_out;
    const int n_edges  = in_sizes[2];
    const int n_atoms  = out_size / NF;

    int* offsets = (int*)d_ws;  // n_atoms + 1 ints

    {
        const int blocks = (n_edges + 255) / 256;
        build_offsets<<<blocks, 256, 0, stream>>>(idx_i, offsets, n_edges, n_atoms);
    }
    {
        const int threads = n_atoms * 16;
        const int blocks  = (threads + 255) / 256;
        cfconv_gather<<<blocks, 256, 0, stream>>>(x, Wij, idx_j, offsets, y, n_atoms);
    }
}

// Round 3
// 454.618 us; speedup vs baseline: 1.1165x; 1.0224x over previous
//
#include <hip/hip_runtime.h>

#define NF 64
typedef float f4 __attribute__((ext_vector_type(4)));

// Pass 1: CSR row offsets from sorted idx_i.
// offsets[a] = lower_bound(idx_i, a); offsets[n_atoms] = n_edges.
__global__ __launch_bounds__(256) void build_offsets(
    const int* __restrict__ idx_i, int* __restrict__ offsets,
    int n_edges, int n_atoms)
{
    const int e = blockIdx.x * blockDim.x + threadIdx.x;
    if (e >= n_edges) return;
    const int cur  = idx_i[e];
    const int prev = (e == 0) ? -1 : idx_i[e - 1];
    for (int a = prev + 1; a <= cur; ++a) offsets[a] = e;
    if (e == n_edges - 1)
        for (int a = cur + 1; a <= n_atoms; ++a) offsets[a] = n_edges;
}

// Pass 2: one 16-lane group per atom; lane owns a 16B feature slice.
// Wij is touched exactly once -> non-temporal loads (keep L2 for the hot
// 25.6 MB x table). y written once -> non-temporal stores. Unroll 4 with
// independent accumulators to keep 4 idx_j->x chains in flight.
__global__ __launch_bounds__(256) void cfconv_gather(
    const float* __restrict__ x, const float* __restrict__ Wij,
    const int* __restrict__ idx_j, const int* __restrict__ offsets,
    float* __restrict__ y, int n_atoms)
{
    const int g    = (blockIdx.x * blockDim.x + threadIdx.x) >> 4;
    const int lane = threadIdx.x & 15;
    if (g >= n_atoms) return;
    const int s = offsets[g];
    const int t = offsets[g + 1];

    const f4* __restrict__ xp = reinterpret_cast<const f4*>(x);    // row j -> xp[j*16 + lane]
    const f4* __restrict__ wp = reinterpret_cast<const f4*>(Wij);  // edge e -> wp[e*16 + lane]

    f4 a0 = 0.f, a1 = 0.f, a2 = 0.f, a3 = 0.f;

    int e = s;
    for (; e + 4 <= t; e += 4) {
        const int j0 = idx_j[e + 0];
        const int j1 = idx_j[e + 1];
        const int j2 = idx_j[e + 2];
        const int j3 = idx_j[e + 3];
        const f4 w0 = __builtin_nontemporal_load(wp + (size_t)(e + 0) * 16 + lane);
        const f4 w1 = __builtin_nontemporal_load(wp + (size_t)(e + 1) * 16 + lane);
        const f4 w2 = __builtin_nontemporal_load(wp + (size_t)(e + 2) * 16 + lane);
        const f4 w3 = __builtin_nontemporal_load(wp + (size_t)(e + 3) * 16 + lane);
        const f4 x0 = xp[(size_t)j0 * 16 + lane];
        const f4 x1 = xp[(size_t)j1 * 16 + lane];
        const f4 x2 = xp[(size_t)j2 * 16 + lane];
        const f4 x3 = xp[(size_t)j3 * 16 + lane];
        a0 += w0 * x0;
        a1 += w1 * x1;
        a2 += w2 * x2;
        a3 += w3 * x3;
    }
    for (; e < t; ++e) {
        const int j0 = idx_j[e];
        const f4 w0 = __builtin_nontemporal_load(wp + (size_t)e * 16 + lane);
        a0 += w0 * xp[(size_t)j0 * 16 + lane];
    }

    a0 = (a0 + a1) + (a2 + a3);
    __builtin_nontemporal_store(a0, reinterpret_cast<f4*>(y) + (size_t)g * 16 + lane);
}

extern "C" void kernel_launch(void* const* d_in, const int* in_sizes, int n_in,
                              void* d_out, int out_size, void* d_ws, size_t ws_size,
                              hipStream_t stream) {
    const float* x     = (const float*)d_in[0];
    const float* Wij   = (const float*)d_in[1];
    const int*   idx_i = (const int*)d_in[2];
    const int*   idx_j = (const int*)d_in[3];
    float*       y     = (float*)d_out;
    const int n_edges  = in_sizes[2];
    const int n_atoms  = out_size / NF;

    int* offsets = (int*)d_ws;  // n_atoms + 1 ints

    {
        const int blocks = (n_edges + 255) / 256;
        build_offsets<<<blocks, 256, 0, stream>>>(idx_i, offsets, n_edges, n_atoms);
    }
    {
        const int threads = n_atoms * 16;
        const int blocks  = (threads + 255) / 256;
        cfconv_gather<<<blocks, 256, 0, stream>>>(x, Wij, idx_j, offsets, y, n_atoms);
    }
}